// Round 6
// baseline (453.700 us; speedup 1.0000x reference)
//
#include <hip/hip_runtime.h>

#define TAGS 128
#define SEQ 1024
#define BATCH 128
#define NGRP 8          // batch groups of 16 (per direction)
#define GB 16           // batches per group
#define SEQB 16         // sequential blocks (8 fwd + 8 bwd)
#define PACKB 16        // packer blocks (one per (grp,dir) stream)
#define GRID_ALL (SEQB + PACKB + BATCH)   // 160 blocks <= 256 CUs: all resident

typedef __attribute__((ext_vector_type(8))) _Float16 half8;
typedef __attribute__((ext_vector_type(2))) _Float16 half2v;
typedef __attribute__((ext_vector_type(4))) float f32x4;

#define GS_BYTES ((size_t)NGRP * SEQ * 64 * 16 * 4)   // 33.5 MB of u32 (f16 pairs)

static __device__ __forceinline__ unsigned pk2u(float a, float b) {
    return __builtin_bit_cast(unsigned, __builtin_amdgcn_cvt_pkrtz(a, b));
}
static __device__ __forceinline__ half2v h2(unsigned u) {
    return __builtin_bit_cast(half2v, u);
}

// ---------------------------------------------------------------------------
// Layout (16x16x32 MFMA, 16-batch chains) -- unchanged from R4.
// Lane L: n = L&15 (batch col), kb = L>>4 (k-block).
// B-frag / state dword slot (sl,d) at lane L holds f16 pair for tags u0,u0+1,
// u0 = 16*(2*sl + (d>>1)) + 4*kb + 2*(d&1).  acc[t][r] (m = 16t+4kb+r) maps
// into slot (sl,d) with t = 2sl+(d>>1), r = 2(d&1): wave W owns rows
// {2W,2W+1}, produces slice W.  gs per (grp,i,lane): 16 dwords [sl][d].
//
// R6: single launch, producer/consumer. Packer stream s (s<8: fwd grp s,
// ascending i; s>=8: bwd grp s-8, descending i) publishes groups of 8
// positions via sync[1+s] (threadfence + agent release RMW). Seq blocks spin
// (agent acquire) every 32 steps; packer outruns consumption ~2x.
// ---------------------------------------------------------------------------

#define EPITCH 66

template<int W>
__device__ __forceinline__ void seq_wave(
    const unsigned* __restrict__ gs, const float* __restrict__ Ain,
    float* __restrict__ Fst, float* __restrict__ Vst,
    float* __restrict__ Cf, float* __restrict__ Cb,
    int* __restrict__ sync, uint4 (&xbuf)[2][4][64])
{
    const int blk = blockIdx.x;
    const bool fwd = blk < NGRP;
    const int grp = fwd ? blk : blk - NGRP;
    const int lane = threadIdx.x & 63;
    const int kb = lane >> 4, n = lane & 15;
    const int sF = fwd ? grp : 8 + grp;       // own stream
    const int sO = 8 + grp;                   // bwd stream (G_512 for fwd)

    auto wait_rdy = [&](int sidx, int need) {
        if (threadIdx.x == 0) {
            while (__hip_atomic_load(&sync[1 + sidx], __ATOMIC_ACQUIRE,
                                     __HIP_MEMORY_SCOPE_AGENT) < need)
                __builtin_amdgcn_s_sleep(8);
        }
        __syncthreads();
    };

    // chain pairing: own slice first, exchanged slices late
    constexpr int cA0 = W, cA1 = (W + 1) & 3, cB0 = (W + 2) & 3, cB1 = (W + 3) & 3;

    auto build_frag = [&](int t, int sl) -> half8 {
        unsigned q[4];
#pragma unroll
        for (int d = 0; d < 4; ++d) {
            int v0 = 16 * (2 * sl + (d >> 1)) + 4 * kb + 2 * (d & 1);
            int m = 16 * t + n;
            float e0, e1;
            if (fwd) { e0 = __expf(Ain[v0 * TAGS + m]);
                       e1 = __expf(Ain[(v0 + 1) * TAGS + m]); }
            else     { e0 = __expf(Ain[m * TAGS + v0]);
                       e1 = __expf(Ain[m * TAGS + v0 + 1]); }
            q[d] = pk2u(e0, e1);
        }
        uint4 qv = make_uint4(q[0], q[1], q[2], q[3]);
        return __builtin_bit_cast(half8, qv);
    };
    half8 afO[2][4];                          // own rows t = 2W, 2W+1
#pragma unroll
    for (int tt = 0; tt < 2; ++tt)
#pragma unroll
        for (int sl = 0; sl < 4; ++sl)
            afO[tt][sl] = build_frag(2 * W + tt, sl);
    half8 af0[4];                             // pivot row-block (waves 1-3)
    if (W != 0)
#pragma unroll
        for (int sl = 0; sl < 4; ++sl)
            af0[sl] = build_frag(0, sl);

    wait_rdy(sF, 5);                          // positions 0..39 of own stream

    // ---- init state from G_0 (fwd) / G_1023 (bwd): pack IS the B-frag ----
    uint4 pksq[4];
    {
        const uint4* g0 = (const uint4*)(gs +
            ((size_t)(grp * SEQ + (fwd ? 0 : SEQ - 1)) * 64 + lane) * 16);
#pragma unroll
        for (int k2 = 0; k2 < 4; ++k2) pksq[k2] = g0[k2];
    }
    float C = 0.f;
    f32x4 acc[2], a0;
    uint4 ghA, ghB;

    // per-(pos,lane) G quarter: uint4 index = (grp*SEQ+idx)*256 + lane*4 + W
    const uint4* gbase = (const uint4*)gs + ((size_t)grp * SEQ * 256 + lane * 4 + W);
    auto load_gh = [&](uint4& g, int idx) { g = gbase[(size_t)idx * 256]; };

    auto mfma_all = [&]() {
        f32x4 z = {0.f, 0.f, 0.f, 0.f};
        half8 bA0 = __builtin_bit_cast(half8, pksq[cA0]);
        half8 bA1 = __builtin_bit_cast(half8, pksq[cA1]);
        half8 bB0 = __builtin_bit_cast(half8, pksq[cB0]);
        half8 bB1 = __builtin_bit_cast(half8, pksq[cB1]);
        f32x4 aA[2], aB[2];
#pragma unroll
        for (int tt = 0; tt < 2; ++tt) {
            aA[tt] = __builtin_amdgcn_mfma_f32_16x16x32_f16(afO[tt][cA0], bA0, z, 0, 0, 0);
            aB[tt] = __builtin_amdgcn_mfma_f32_16x16x32_f16(afO[tt][cB0], bB0, z, 0, 0, 0);
        }
#pragma unroll
        for (int tt = 0; tt < 2; ++tt) {
            aA[tt] = __builtin_amdgcn_mfma_f32_16x16x32_f16(afO[tt][cA1], bA1, aA[tt], 0, 0, 0);
            aB[tt] = __builtin_amdgcn_mfma_f32_16x16x32_f16(afO[tt][cB1], bB1, aB[tt], 0, 0, 0);
        }
        if (W == 0) {
#pragma unroll
            for (int tt = 0; tt < 2; ++tt) acc[tt] = aA[tt] + aB[tt];
            a0 = acc[0];
        } else {
            half8 p0 = __builtin_bit_cast(half8, pksq[0]);
            half8 p1 = __builtin_bit_cast(half8, pksq[1]);
            half8 p2 = __builtin_bit_cast(half8, pksq[2]);
            half8 p3 = __builtin_bit_cast(half8, pksq[3]);
            f32x4 pe = __builtin_amdgcn_mfma_f32_16x16x32_f16(af0[0], p0, z, 0, 0, 0);
            f32x4 po = __builtin_amdgcn_mfma_f32_16x16x32_f16(af0[2], p2, z, 0, 0, 0);
            pe = __builtin_amdgcn_mfma_f32_16x16x32_f16(af0[1], p1, pe, 0, 0, 0);
            po = __builtin_amdgcn_mfma_f32_16x16x32_f16(af0[3], p3, po, 0, 0, 0);
#pragma unroll
            for (int tt = 0; tt < 2; ++tt) acc[tt] = aA[tt] + aB[tt];
            a0 = pe + po;
        }
    };

    auto step = [&](const uint4& gh, int pb) {
        mfma_all();
        float q0 = __shfl(a0[0], n, 64);      // D[0][n] lives in lane n
        float rn = __builtin_amdgcn_rcpf(q0) * 0.0625f;   // 2^-4 headroom
        C += __logf(q0) + 2.7725887222397812f;            // + log(16)
        const unsigned* gu = (const unsigned*)&gh;
        unsigned pko[4];
#pragma unroll
        for (int d = 0; d < 4; ++d) {
            int tt = d >> 1, r = 2 * (d & 1);
            half2v hv = __builtin_bit_cast(half2v,
                pk2u(acc[tt][r] * rn, acc[tt][r + 1] * rn));
            half2v g2 = h2(gu[d]);
            hv = hv * g2;
            pko[d] = __builtin_bit_cast(unsigned, hv);
        }
        uint4 o0 = make_uint4(pko[0], pko[1], pko[2], pko[3]);
        pksq[W] = o0;                         // compile-time index
        xbuf[pb][W][lane] = o0;               // 16B/lane contiguous: conflict-free
        __syncthreads();
#pragma unroll
        for (int s = 0; s < 4; ++s)
            if (s != W) pksq[s] = xbuf[pb][s][lane];
    };

    if (fwd) {
        load_gh(ghA, 1); load_gh(ghB, 2);
#pragma unroll 1
        for (int j = 1; j <= 509; j += 2) {   // steps 1..510
            if (((j - 1) & 31) == 0 && j > 1) {
                const int c = (j - 1) >> 5;
                const int need = c * 4 + 5;
                wait_rdy(sF, need > 64 ? 64 : need);
                if (c == 15) wait_rdy(sO, 64);   // G_512 from bwd stream
            }
            step(ghA, 1); load_gh(ghA, j + 2);
            step(ghB, 0); load_gh(ghB, j + 3);
        }
        step(ghA, 1);                         // step 511 (ghA = G_511)
        mfma_all();                           // peeled step 512
        {
            float q0 = __shfl(a0[0], n, 64);
            float rn = __builtin_amdgcn_rcpf(q0);
            C += __logf(q0);
            const unsigned* gu = (const unsigned*)&ghB;  // G_512 own quarter
            const int b = grp * GB + n;
#pragma unroll
            for (int tt = 0; tt < 2; ++tt) {
                const int t = 2 * W + tt;
                half2v ga = h2(gu[2 * tt]);
                half2v gb = h2(gu[2 * tt + 1]);
                float4 wv;
                wv.x = acc[tt][0] * rn * (float)ga[0];
                wv.y = acc[tt][1] * rn * (float)ga[1];
                wv.z = acc[tt][2] * rn * (float)gb[0];
                wv.w = acc[tt][3] * rn * (float)gb[1];
                *(float4*)&Fst[(size_t)b * TAGS + 16 * t + 4 * kb] = wv;
            }
            if (W == 0 && kb == 0) Cf[b] = C;
        }
    } else {
        load_gh(ghA, 1022); load_gh(ghB, 1021);
#pragma unroll 1
        for (int j = 1; j <= 507; j += 2) {   // epis G_1022..G_515
            if (((j - 1) & 31) == 0 && j > 1) {
                const int c = (j - 1) >> 5;
                const int need = c * 4 + 5;
                wait_rdy(sF, need > 64 ? 64 : need);
            }
            step(ghA, 1); load_gh(ghA, 1023 - (j + 2));
            step(ghB, 0); load_gh(ghB, 1023 - (j + 3));
        }
        step(ghA, 1);                         // epi G_514
        step(ghB, 0);                         // epi G_513
        mfma_all();                           // peeled: beta_512
        {
            float q0 = __shfl(a0[0], n, 64);
            float rn = __builtin_amdgcn_rcpf(q0);
            C += __logf(q0);
            const int b = grp * GB + n;
#pragma unroll
            for (int tt = 0; tt < 2; ++tt) {
                const int t = 2 * W + tt;
                float4 wv;
                wv.x = acc[tt][0] * rn; wv.y = acc[tt][1] * rn;
                wv.z = acc[tt][2] * rn; wv.w = acc[tt][3] * rn;
                *(float4*)&Vst[(size_t)b * TAGS + 16 * t + 4 * kb] = wv;
            }
            if (W == 0 && kb == 0) Cb[b] = C;
        }
    }
}

// ---------------------------------------------------------------------------
// One launch, three roles:
//   blocks 0..15   : seq chains (4 waves, templated role) + last-block combine
//   blocks 16..31  : packers, stream s = blk-16, 8 positions/iter in order
//   blocks 32..159 : gold-path score (one batch each)
// ---------------------------------------------------------------------------
__global__ __launch_bounds__(256, 1)
void crf_all(const float* __restrict__ yp, const int* __restrict__ yt,
             const float* __restrict__ mask, const float* __restrict__ Ain,
             unsigned* __restrict__ gs,
             float* __restrict__ Fst, float* __restrict__ Vst,
             float* __restrict__ Cf, float* __restrict__ Cb,
             float* __restrict__ out, int* __restrict__ sync)
{
    __shared__ unsigned ldsT[8][GB * EPITCH];  // pack transpose tiles (33.8 KB)
    __shared__ uint4 xbuf[2][4][64];           // seq exchange (8 KB)
    __shared__ float wred[4];
    __shared__ int lastf;
    const int blk = blockIdx.x;
    const int tid = threadIdx.x;

    if (blk >= SEQB + PACKB) {                 // ---- score role ----
        const int b = blk - (SEQB + PACKB);
        const float* __restrict__ ypb = yp + (size_t)b * SEQ * TAGS;
        const float* __restrict__ mb  = mask + (size_t)b * SEQ;
        const int*   __restrict__ ytb = yt + (size_t)b * SEQ;
        float sc = 0.f;
#pragma unroll
        for (int k = 0; k < SEQ / 256; ++k) {
            int s = tid + k * 256;
            int l = ytb[s];
            float m = mb[s];
            sc += ypb[(size_t)s * TAGS + l] * m;
            if (s + 1 < SEQ) {
                int l2 = ytb[s + 1];
                sc += Ain[l * TAGS + l2] * m * mb[s + 1];
            }
        }
#pragma unroll
        for (int off = 32; off > 0; off >>= 1)
            sc += __shfl_down(sc, off, 64);
        if ((tid & 63) == 0) wred[tid >> 6] = sc;
        __syncthreads();
        if (tid == 0)
            atomicAdd(out, -(wred[0] + wred[1] + wred[2] + wred[3])
                               * (1.0f / (float)BATCH));
        return;
    }

    if (blk >= SEQB) {                         // ---- packer role ----
        const int s = blk - SEQB;
        const bool pfwd = s < 8;
        const int pgrp = pfwd ? s : s - 8;
        const int wv = tid >> 6, lt = tid & 63;
        const int pkb = lt >> 4, pn = lt & 15;
#pragma unroll 1
        for (int k = 0; k < 64; ++k) {         // 8 positions per iteration
#pragma unroll
            for (int pp = 0; pp < 2; ++pp) {   // phase A: read+exp+stage
                const int p = 8 * k + 2 * wv + pp;
                const int i = pfwd ? p : 1023 - p;
                const float* src = yp + (size_t)(pgrp * GB) * SEQ * TAGS
                                      + (size_t)i * TAGS;
                unsigned* tile = ldsT[2 * wv + pp];
#pragma unroll
                for (int kk = 0; kk < 8; ++kk) {
                    int f = lt + 64 * kk;
                    int r = f >> 5, c2 = f & 31;
                    const float4 v = *(const float4*)(src + (size_t)r * SEQ * TAGS + 4 * c2);
                    uint2 d;
                    d.x = pk2u(__expf(v.x), __expf(v.y));
                    d.y = pk2u(__expf(v.z), __expf(v.w));
                    *(uint2*)&tile[r * EPITCH + 2 * c2] = d;
                }
            }
#pragma unroll
            for (int pp = 0; pp < 2; ++pp) {   // phase B: permuted gather+store
                const int p = 8 * k + 2 * wv + pp;
                const int i = pfwd ? p : 1023 - p;
                const unsigned* tile = ldsT[2 * wv + pp];
                unsigned* dst = gs + ((size_t)(pgrp * SEQ + i) * 64 + lt) * 16;
                uint2 w2[8];
#pragma unroll
                for (int sl = 0; sl < 4; ++sl)
#pragma unroll
                    for (int dd = 0; dd < 2; ++dd) {
                        int t = 2 * sl + dd;
                        int pu = 8 * t + 2 * pkb;
                        w2[2 * sl + dd] = *(const uint2*)&tile[pn * EPITCH + pu];
                    }
#pragma unroll
                for (int q = 0; q < 4; ++q)
                    ((uint4*)dst)[q] = make_uint4(w2[2 * q].x, w2[2 * q].y,
                                                  w2[2 * q + 1].x, w2[2 * q + 1].y);
            }
            __threadfence();                   // this thread's stores visible
            __syncthreads();                   // whole group-k fenced
            if (tid == 0)
                __hip_atomic_fetch_add(&sync[1 + s], 1, __ATOMIC_RELEASE,
                                       __HIP_MEMORY_SCOPE_AGENT);
        }
        return;
    }

    // ---- seq role ----
    {
        const int w = tid >> 6;
        if      (w == 0) seq_wave<0>(gs, Ain, Fst, Vst, Cf, Cb, sync, xbuf);
        else if (w == 1) seq_wave<1>(gs, Ain, Fst, Vst, Cf, Cb, sync, xbuf);
        else if (w == 2) seq_wave<2>(gs, Ain, Fst, Vst, Cf, Cb, sync, xbuf);
        else             seq_wave<3>(gs, Ain, Fst, Vst, Cf, Cb, sync, xbuf);

        __syncthreads();
        __threadfence();                       // release Fst/Vst/Cf/Cb
        if (tid == 0)
            lastf = (__hip_atomic_fetch_add(&sync[0], 1, __ATOMIC_ACQ_REL,
                                            __HIP_MEMORY_SCOPE_AGENT) == SEQB - 1);
        __syncthreads();
        if (lastf) {
            __threadfence();                   // acquire
            if (tid < BATCH) {
                const int b = tid;
                const float* f = Fst + (size_t)b * TAGS;
                const float* v = Vst + (size_t)b * TAGS;
                float sdot = 0.f;
#pragma unroll
                for (int u = 0; u < TAGS; ++u) sdot += f[u] * v[u];
                float logZ = Cf[b] + Cb[b] + __logf(sdot);
                atomicAdd(out, logZ * (1.0f / (float)BATCH));
            }
        }
    }
}

extern "C" void kernel_launch(void* const* d_in, const int* in_sizes, int n_in,
                              void* d_out, int out_size, void* d_ws, size_t ws_size,
                              hipStream_t stream) {
    const float* yp   = (const float*)d_in[0];   // (128,1024,128) f32
    const int*   yt   = (const int*)d_in[1];     // (128,1024) int
    const float* mask = (const float*)d_in[2];   // (128,1024) f32
    const float* A    = (const float*)d_in[3];   // (128,128) f32
    float* out = (float*)d_out;

    unsigned* gs = (unsigned*)d_ws;
    float* Fst = (float*)((char*)d_ws + GS_BYTES);
    float* Vst = Fst + BATCH * TAGS;
    float* Cf  = Vst + BATCH * TAGS;
    float* Cb  = Cf + BATCH;
    int*   sync = (int*)(Cb + BATCH);            // [0]=seq cnt, [1..16]=rdy

    (void)hipMemsetAsync(out, 0, sizeof(float), stream);
    (void)hipMemsetAsync(sync, 0, (1 + PACKB) * sizeof(int), stream);
    crf_all<<<GRID_ALL, 256, 0, stream>>>(yp, yt, mask, A, gs,
                                          Fst, Vst, Cf, Cb, out, sync);
}

// Round 7
// 312.013 us; speedup vs baseline: 1.4541x; 1.4541x over previous
//
#include <hip/hip_runtime.h>

#define TAGS 128
#define SEQ 1024
#define BATCH 128
#define NGRP 8          // batch groups of 16 (per direction)
#define GB 16           // batches per group
#define SEQB 16         // sequential blocks (8 fwd + 8 bwd)
#define GRID_ALL 256    // all-resident: 256 blocks on 256 CUs

typedef __attribute__((ext_vector_type(8))) _Float16 half8;
typedef __attribute__((ext_vector_type(2))) _Float16 half2v;
typedef __attribute__((ext_vector_type(4))) float f32x4;

#define GS_BYTES ((size_t)NGRP * SEQ * 64 * 16 * 4)   // 33.5 MB of u32 (f16 pairs)

static __device__ __forceinline__ unsigned pk2u(float a, float b) {
    return __builtin_bit_cast(unsigned, __builtin_amdgcn_cvt_pkrtz(a, b));
}
static __device__ __forceinline__ half2v h2(unsigned u) {
    return __builtin_bit_cast(half2v, u);
}

// ---------------------------------------------------------------------------
// Layout (16x16x32 MFMA, 16-batch chains) -- R4's verified scheme.
// Lane L: n = L&15 (batch col), kb = L>>4 (k-block).
// B-frag / state dword slot (sl,d) at lane L holds f16 pair for tags u0,u0+1,
// u0 = 16*(2*sl + (d>>1)) + 4*kb + 2*(d&1).  acc[t][r] (m = 16t+4kb+r) maps
// into slot (sl,d) with t = 2sl+(d>>1), r = 2(d&1): wave W owns rows
// {2W,2W+1}, produces slice W.  gs per (grp,i,lane): 16 dwords [sl][d].
//
// R7: ONE dispatch. Phase 0: ALL 256 blocks pack a grid-strided slice of the
// 8192 positions -- register-only permuted read (lane (kb,n): row n, float4
// at col 16t+4kb IS slot (sl=t>>1, dd=t&1)), no LDS, each position packed
// exactly once (R6 bug: 2x). Packers signal agent-scope counter; only the 16
// seq blocks spin (score never reads gs; 240 runnable blocks -> no deadlock,
// all 256 blocks co-resident). Then R4's seq (pivot normalizer, 712 cyc/step)
// + concurrent score + combine-by-last (R5's validated pattern).
// ---------------------------------------------------------------------------

template<int W>
__device__ __forceinline__ void seq_wave(
    const unsigned* __restrict__ gs, const float* __restrict__ Ain,
    float* __restrict__ Fst, float* __restrict__ Vst,
    float* __restrict__ Cf, float* __restrict__ Cb,
    uint4 (&xbuf)[2][4][64])
{
    const int blk = blockIdx.x;
    const bool fwd = blk < NGRP;
    const int grp = fwd ? blk : blk - NGRP;
    const int lane = threadIdx.x & 63;
    const int kb = lane >> 4, n = lane & 15;

    // chain pairing: own slice first, exchanged slices late
    constexpr int cA0 = W, cA1 = (W + 1) & 3, cB0 = (W + 2) & 3, cB1 = (W + 3) & 3;

    auto build_frag = [&](int t, int sl) -> half8 {
        unsigned q[4];
#pragma unroll
        for (int d = 0; d < 4; ++d) {
            int v0 = 16 * (2 * sl + (d >> 1)) + 4 * kb + 2 * (d & 1);
            int m = 16 * t + n;
            float e0, e1;
            if (fwd) { e0 = __expf(Ain[v0 * TAGS + m]);
                       e1 = __expf(Ain[(v0 + 1) * TAGS + m]); }
            else     { e0 = __expf(Ain[m * TAGS + v0]);
                       e1 = __expf(Ain[m * TAGS + v0 + 1]); }
            q[d] = pk2u(e0, e1);
        }
        uint4 qv = make_uint4(q[0], q[1], q[2], q[3]);
        return __builtin_bit_cast(half8, qv);
    };
    half8 afO[2][4];                          // own rows t = 2W, 2W+1
#pragma unroll
    for (int tt = 0; tt < 2; ++tt)
#pragma unroll
        for (int sl = 0; sl < 4; ++sl)
            afO[tt][sl] = build_frag(2 * W + tt, sl);
    half8 af0[4];                             // pivot row-block (waves 1-3)
    if (W != 0)
#pragma unroll
        for (int sl = 0; sl < 4; ++sl)
            af0[sl] = build_frag(0, sl);

    // ---- init state from G_0 (fwd) / G_1023 (bwd): pack IS the B-frag ----
    uint4 pksq[4];
    {
        const uint4* g0 = (const uint4*)(gs +
            ((size_t)(grp * SEQ + (fwd ? 0 : SEQ - 1)) * 64 + lane) * 16);
#pragma unroll
        for (int k2 = 0; k2 < 4; ++k2) pksq[k2] = g0[k2];
    }
    float C = 0.f;
    f32x4 acc[2], a0;
    uint4 ghA, ghB;

    // per-(pos,lane) G quarter: uint4 index = (grp*SEQ+idx)*256 + lane*4 + W
    const uint4* gbase = (const uint4*)gs + ((size_t)grp * SEQ * 256 + lane * 4 + W);
    auto load_gh = [&](uint4& g, int idx) { g = gbase[(size_t)idx * 256]; };

    auto mfma_all = [&]() {
        f32x4 z = {0.f, 0.f, 0.f, 0.f};
        half8 bA0 = __builtin_bit_cast(half8, pksq[cA0]);
        half8 bA1 = __builtin_bit_cast(half8, pksq[cA1]);
        half8 bB0 = __builtin_bit_cast(half8, pksq[cB0]);
        half8 bB1 = __builtin_bit_cast(half8, pksq[cB1]);
        f32x4 aA[2], aB[2];
#pragma unroll
        for (int tt = 0; tt < 2; ++tt) {
            aA[tt] = __builtin_amdgcn_mfma_f32_16x16x32_f16(afO[tt][cA0], bA0, z, 0, 0, 0);
            aB[tt] = __builtin_amdgcn_mfma_f32_16x16x32_f16(afO[tt][cB0], bB0, z, 0, 0, 0);
        }
#pragma unroll
        for (int tt = 0; tt < 2; ++tt) {
            aA[tt] = __builtin_amdgcn_mfma_f32_16x16x32_f16(afO[tt][cA1], bA1, aA[tt], 0, 0, 0);
            aB[tt] = __builtin_amdgcn_mfma_f32_16x16x32_f16(afO[tt][cB1], bB1, aB[tt], 0, 0, 0);
        }
        if (W == 0) {
#pragma unroll
            for (int tt = 0; tt < 2; ++tt) acc[tt] = aA[tt] + aB[tt];
            a0 = acc[0];
        } else {
            half8 p0 = __builtin_bit_cast(half8, pksq[0]);
            half8 p1 = __builtin_bit_cast(half8, pksq[1]);
            half8 p2 = __builtin_bit_cast(half8, pksq[2]);
            half8 p3 = __builtin_bit_cast(half8, pksq[3]);
            f32x4 pe = __builtin_amdgcn_mfma_f32_16x16x32_f16(af0[0], p0, z, 0, 0, 0);
            f32x4 po = __builtin_amdgcn_mfma_f32_16x16x32_f16(af0[2], p2, z, 0, 0, 0);
            pe = __builtin_amdgcn_mfma_f32_16x16x32_f16(af0[1], p1, pe, 0, 0, 0);
            po = __builtin_amdgcn_mfma_f32_16x16x32_f16(af0[3], p3, po, 0, 0, 0);
#pragma unroll
            for (int tt = 0; tt < 2; ++tt) acc[tt] = aA[tt] + aB[tt];
            a0 = pe + po;
        }
    };

    auto step = [&](const uint4& gh, int pb) {
        mfma_all();
        float q0 = __shfl(a0[0], n, 64);      // D[0][n] lives in lane n
        float rn = __builtin_amdgcn_rcpf(q0) * 0.0625f;   // 2^-4 headroom
        C += __logf(q0) + 2.7725887222397812f;            // + log(16)
        const unsigned* gu = (const unsigned*)&gh;
        unsigned pko[4];
#pragma unroll
        for (int d = 0; d < 4; ++d) {
            int tt = d >> 1, r = 2 * (d & 1);
            half2v hv = __builtin_bit_cast(half2v,
                pk2u(acc[tt][r] * rn, acc[tt][r + 1] * rn));
            half2v g2 = h2(gu[d]);
            hv = hv * g2;
            pko[d] = __builtin_bit_cast(unsigned, hv);
        }
        uint4 o0 = make_uint4(pko[0], pko[1], pko[2], pko[3]);
        pksq[W] = o0;                         // compile-time index
        xbuf[pb][W][lane] = o0;               // 16B/lane contiguous: conflict-free
        __syncthreads();
#pragma unroll
        for (int s = 0; s < 4; ++s)
            if (s != W) pksq[s] = xbuf[pb][s][lane];
    };

    if (fwd) {
        load_gh(ghA, 1); load_gh(ghB, 2);
#pragma unroll 1
        for (int j = 1; j <= 509; j += 2) {   // steps 1..510
            step(ghA, 1); load_gh(ghA, j + 2);
            step(ghB, 0); load_gh(ghB, j + 3);
        }
        step(ghA, 1);                         // step 511 (ghA = G_511)
        mfma_all();                           // peeled step 512
        {
            float q0 = __shfl(a0[0], n, 64);
            float rn = __builtin_amdgcn_rcpf(q0);
            C += __logf(q0);
            const unsigned* gu = (const unsigned*)&ghB;  // G_512 own quarter
            const int b = grp * GB + n;
#pragma unroll
            for (int tt = 0; tt < 2; ++tt) {
                const int t = 2 * W + tt;
                half2v ga = h2(gu[2 * tt]);
                half2v gb = h2(gu[2 * tt + 1]);
                float4 wv;
                wv.x = acc[tt][0] * rn * (float)ga[0];
                wv.y = acc[tt][1] * rn * (float)ga[1];
                wv.z = acc[tt][2] * rn * (float)gb[0];
                wv.w = acc[tt][3] * rn * (float)gb[1];
                *(float4*)&Fst[(size_t)b * TAGS + 16 * t + 4 * kb] = wv;
            }
            if (W == 0 && kb == 0) Cf[b] = C;
        }
    } else {
        load_gh(ghA, 1022); load_gh(ghB, 1021);
#pragma unroll 1
        for (int j = 1; j <= 507; j += 2) {   // epis G_1022..G_515
            step(ghA, 1); load_gh(ghA, 1023 - (j + 2));
            step(ghB, 0); load_gh(ghB, 1023 - (j + 3));
        }
        step(ghA, 1);                         // epi G_514
        step(ghB, 0);                         // epi G_513
        mfma_all();                           // peeled: beta_512
        {
            float q0 = __shfl(a0[0], n, 64);
            float rn = __builtin_amdgcn_rcpf(q0);
            C += __logf(q0);
            const int b = grp * GB + n;
#pragma unroll
            for (int tt = 0; tt < 2; ++tt) {
                const int t = 2 * W + tt;
                float4 wv;
                wv.x = acc[tt][0] * rn; wv.y = acc[tt][1] * rn;
                wv.z = acc[tt][2] * rn; wv.w = acc[tt][3] * rn;
                *(float4*)&Vst[(size_t)b * TAGS + 16 * t + 4 * kb] = wv;
            }
            if (W == 0 && kb == 0) Cb[b] = C;
        }
    }
}

// ---------------------------------------------------------------------------
// One dispatch: phase 0 everyone packs; then blocks 0..15 seq (+combine by
// last), blocks 16..143 score, blocks 144..255 exit after packing.
// ---------------------------------------------------------------------------
__global__ __launch_bounds__(256, 1)
void crf_all(const float* __restrict__ yp, const int* __restrict__ yt,
             const float* __restrict__ mask, const float* __restrict__ Ain,
             unsigned* __restrict__ gs,
             float* __restrict__ Fst, float* __restrict__ Vst,
             float* __restrict__ Cf, float* __restrict__ Cb,
             float* __restrict__ out, int* __restrict__ sync)
{
    __shared__ uint4 xbuf[2][4][64];          // seq exchange (8 KB)
    __shared__ float wred[4];
    __shared__ int lastf;
    const int blk = blockIdx.x;
    const int tid = threadIdx.x;
    const int wv = tid >> 6, lane = tid & 63;
    const int kb = lane >> 4, n = lane & 15;

    // ---- phase 0: grid-strided register-only pack (8 positions/wave) ----
#pragma unroll 1
    for (int p = blk * 4 + wv; p < NGRP * SEQ; p += GRID_ALL * 4) {
        const int grp = p >> 10, i = p & (SEQ - 1);
        const float* src = yp + ((size_t)(grp * GB + n)) * SEQ * TAGS
                              + (size_t)i * TAGS + 4 * kb;
        uint4 o[4];
#pragma unroll
        for (int sl = 0; sl < 4; ++sl) {
            const float4 v0 = *(const float4*)(src + 16 * (2 * sl));
            const float4 v1 = *(const float4*)(src + 16 * (2 * sl + 1));
            o[sl] = make_uint4(pk2u(__expf(v0.x), __expf(v0.y)),
                               pk2u(__expf(v0.z), __expf(v0.w)),
                               pk2u(__expf(v1.x), __expf(v1.y)),
                               pk2u(__expf(v1.z), __expf(v1.w)));
        }
        uint4* dst = (uint4*)(gs + ((size_t)p * 64 + lane) * 16);
#pragma unroll
        for (int q = 0; q < 4; ++q) dst[q] = o[q];
    }
    __threadfence();                          // make gs stores visible (agent)
    __syncthreads();
    if (tid == 0)
        __hip_atomic_fetch_add(&sync[0], 1, __ATOMIC_RELEASE,
                               __HIP_MEMORY_SCOPE_AGENT);

    if (blk >= SEQB + BATCH) return;          // pure packer blocks

    if (blk >= SEQB) {                        // ---- score role (no gs read) ----
        const int b = blk - SEQB;
        const float* __restrict__ ypb = yp + (size_t)b * SEQ * TAGS;
        const float* __restrict__ mb  = mask + (size_t)b * SEQ;
        const int*   __restrict__ ytb = yt + (size_t)b * SEQ;
        float sc = 0.f;
#pragma unroll
        for (int k = 0; k < SEQ / 256; ++k) {
            int s = tid + k * 256;
            int l = ytb[s];
            float m = mb[s];
            sc += ypb[(size_t)s * TAGS + l] * m;
            if (s + 1 < SEQ) {
                int l2 = ytb[s + 1];
                sc += Ain[l * TAGS + l2] * m * mb[s + 1];
            }
        }
#pragma unroll
        for (int off = 32; off > 0; off >>= 1)
            sc += __shfl_down(sc, off, 64);
        if ((tid & 63) == 0) wred[tid >> 6] = sc;
        __syncthreads();
        if (tid == 0)
            atomicAdd(out, -(wred[0] + wred[1] + wred[2] + wred[3])
                               * (1.0f / (float)BATCH));
        return;
    }

    // ---- seq role: wait until ALL blocks finished packing ----
    if (tid == 0) {
        while (__hip_atomic_load(&sync[0], __ATOMIC_ACQUIRE,
                                 __HIP_MEMORY_SCOPE_AGENT) < GRID_ALL)
            __builtin_amdgcn_s_sleep(8);
    }
    __syncthreads();

    {
        const int w = tid >> 6;
        if      (w == 0) seq_wave<0>(gs, Ain, Fst, Vst, Cf, Cb, xbuf);
        else if (w == 1) seq_wave<1>(gs, Ain, Fst, Vst, Cf, Cb, xbuf);
        else if (w == 2) seq_wave<2>(gs, Ain, Fst, Vst, Cf, Cb, xbuf);
        else             seq_wave<3>(gs, Ain, Fst, Vst, Cf, Cb, xbuf);
    }

    // ---- combine by last-finishing seq block ----
    __syncthreads();
    __threadfence();                          // release Fst/Vst/Cf/Cb
    if (tid == 0)
        lastf = (__hip_atomic_fetch_add(&sync[1], 1, __ATOMIC_ACQ_REL,
                                        __HIP_MEMORY_SCOPE_AGENT) == SEQB - 1);
    __syncthreads();
    if (lastf) {
        __threadfence();                      // acquire
        if (tid < BATCH) {
            const int b = tid;
            const float* f = Fst + (size_t)b * TAGS;
            const float* v = Vst + (size_t)b * TAGS;
            float sdot = 0.f;
#pragma unroll
            for (int u = 0; u < TAGS; ++u) sdot += f[u] * v[u];
            float logZ = Cf[b] + Cb[b] + __logf(sdot);
            atomicAdd(out, logZ * (1.0f / (float)BATCH));
        }
    }
}

extern "C" void kernel_launch(void* const* d_in, const int* in_sizes, int n_in,
                              void* d_out, int out_size, void* d_ws, size_t ws_size,
                              hipStream_t stream) {
    const float* yp   = (const float*)d_in[0];   // (128,1024,128) f32
    const int*   yt   = (const int*)d_in[1];     // (128,1024) int
    const float* mask = (const float*)d_in[2];   // (128,1024) f32
    const float* A    = (const float*)d_in[3];   // (128,128) f32
    float* out = (float*)d_out;

    unsigned* gs = (unsigned*)d_ws;
    float* Fst = (float*)((char*)d_ws + GS_BYTES);
    float* Vst = Fst + BATCH * TAGS;
    float* Cf  = Vst + BATCH * TAGS;
    float* Cb  = Cf + BATCH;
    int*   sync = (int*)(Cb + BATCH);            // [0]=pack done, [1]=seq done

    (void)hipMemsetAsync(out, 0, sizeof(float), stream);
    (void)hipMemsetAsync(sync, 0, 2 * sizeof(int), stream);
    crf_all<<<GRID_ALL, 256, 0, stream>>>(yp, yt, mask, A, gs,
                                          Fst, Vst, Cf, Cb, out, sync);
}